// Round 1
// baseline (1536.273 us; speedup 1.0000x reference)
//
#include <hip/hip_runtime.h>

// GCN layer: out = relu(degree_norm * (adj @ (x @ W)) + b)
//   x:   [16384, 128] f32     adj: [16384, 16384] f32 (1 GiB -- the bottleneck)
//   dn:  [16384, 1]   f32     W:   [128, 64] f32       b: [64] f32
//   out: [16384, 64]  f32
//
// Strategy: stage supportT = (x@W)^T as bf16 in ws (2 MiB), then a
// memory-bound MFMA pass over adj (fp32 -> bf16 in-register), fused epilogue.

#define N_NODES 16384
#define FEAT    128
#define HID     64

typedef __attribute__((ext_vector_type(4))) float f32x4;
typedef __attribute__((ext_vector_type(8))) short bf16x8;

__device__ __forceinline__ unsigned short f2bf(float f) {
  // round-to-nearest-even f32 -> bf16 (finite inputs only)
  unsigned int u = __float_as_uint(f);
  u += 0x7fffu + ((u >> 16) & 1u);
  return (unsigned short)(u >> 16);
}

// Kernel 1: supportT[h][m] = sum_f x[m][f] * W[f][h], stored bf16.
// One wave per node m; lane = h. W (32 KiB) stays L1-resident.
__global__ __launch_bounds__(256) void support_kernel(
    const float* __restrict__ x, const float* __restrict__ W,
    unsigned short* __restrict__ supportT) {
  const int lane = threadIdx.x & 63;
  const int wave = threadIdx.x >> 6;
  const int m = blockIdx.x * 4 + wave;
  const f32x4* x4 = (const f32x4*)(x + (size_t)m * FEAT);
  float acc = 0.f;
#pragma unroll
  for (int i = 0; i < FEAT / 4; ++i) {
    f32x4 xv = x4[i];
    const float* wrow = W + (size_t)(i * 4) * HID + lane;
    acc += xv.x * wrow[0 * HID];
    acc += xv.y * wrow[1 * HID];
    acc += xv.z * wrow[2 * HID];
    acc += xv.w * wrow[3 * HID];
  }
  supportT[(size_t)lane * N_NODES + m] = f2bf(acc);
}

// Kernel 2: agg = adj @ support via 16x16x32 bf16 MFMA, fused
// dn*agg + b + relu epilogue. Block = 4 waves x 16 rows = 64 rows.
// A fragments loaded straight from global (fp32, cvt to bf16 in-register);
// B fragments from bf16 supportT (B^T layout -> contiguous 16 B per lane).
__global__ __launch_bounds__(256) void gcn_agg_kernel(
    const float* __restrict__ adj, const unsigned short* __restrict__ supT,
    const float* __restrict__ dn, const float* __restrict__ bias,
    float* __restrict__ out) {
  const int lane = threadIdx.x & 63;
  const int wave = threadIdx.x >> 6;
  const int row0 = blockIdx.x * 64 + wave * 16;
  const int lm = lane & 15;   // A: row within 16-tile / B: col within n-tile
  const int lg = lane >> 4;   // k-group 0..3 (k = lg*8 + j)

  const float* aptr = adj + (size_t)(row0 + lm) * N_NODES + lg * 8;
  const unsigned short* b0 = supT + (size_t)(0 * 16 + lm) * N_NODES + lg * 8;
  const unsigned short* b1 = supT + (size_t)(1 * 16 + lm) * N_NODES + lg * 8;
  const unsigned short* b2 = supT + (size_t)(2 * 16 + lm) * N_NODES + lg * 8;
  const unsigned short* b3 = supT + (size_t)(3 * 16 + lm) * N_NODES + lg * 8;

  f32x4 acc0 = {0.f, 0.f, 0.f, 0.f};
  f32x4 acc1 = acc0, acc2 = acc0, acc3 = acc0;

#pragma unroll 4
  for (int k = 0; k < N_NODES; k += 32) {
    f32x4 alo = *(const f32x4*)(aptr);
    f32x4 ahi = *(const f32x4*)(aptr + 4);
    bf16x8 fb0 = *(const bf16x8*)(b0);
    bf16x8 fb1 = *(const bf16x8*)(b1);
    bf16x8 fb2 = *(const bf16x8*)(b2);
    bf16x8 fb3 = *(const bf16x8*)(b3);
    bf16x8 fa;
    fa[0] = (short)f2bf(alo.x);
    fa[1] = (short)f2bf(alo.y);
    fa[2] = (short)f2bf(alo.z);
    fa[3] = (short)f2bf(alo.w);
    fa[4] = (short)f2bf(ahi.x);
    fa[5] = (short)f2bf(ahi.y);
    fa[6] = (short)f2bf(ahi.z);
    fa[7] = (short)f2bf(ahi.w);
    acc0 = __builtin_amdgcn_mfma_f32_16x16x32_bf16(fa, fb0, acc0, 0, 0, 0);
    acc1 = __builtin_amdgcn_mfma_f32_16x16x32_bf16(fa, fb1, acc1, 0, 0, 0);
    acc2 = __builtin_amdgcn_mfma_f32_16x16x32_bf16(fa, fb2, acc2, 0, 0, 0);
    acc3 = __builtin_amdgcn_mfma_f32_16x16x32_bf16(fa, fb3, acc3, 0, 0, 0);
    aptr += 32;
    b0 += 32; b1 += 32; b2 += 32; b3 += 32;
  }

  // Epilogue. C/D layout (verified m89/m91): col = lane&15, row = (lane>>4)*4 + reg.
  const float bb0 = bias[0 + lm];
  const float bb1 = bias[16 + lm];
  const float bb2 = bias[32 + lm];
  const float bb3 = bias[48 + lm];
  const int orow = row0 + lg * 4;
#pragma unroll
  for (int r = 0; r < 4; ++r) {
    const int rr = orow + r;
    const float d = dn[rr];
    float* op = out + (size_t)rr * HID;
    float v;
    v = d * acc0[r] + bb0; op[0 + lm]  = v > 0.f ? v : 0.f;
    v = d * acc1[r] + bb1; op[16 + lm] = v > 0.f ? v : 0.f;
    v = d * acc2[r] + bb2; op[32 + lm] = v > 0.f ? v : 0.f;
    v = d * acc3[r] + bb3; op[48 + lm] = v > 0.f ? v : 0.f;
  }
}

extern "C" void kernel_launch(void* const* d_in, const int* in_sizes, int n_in,
                              void* d_out, int out_size, void* d_ws, size_t ws_size,
                              hipStream_t stream) {
  const float* x   = (const float*)d_in[0];
  const float* adj = (const float*)d_in[1];
  const float* dn  = (const float*)d_in[2];
  const float* W   = (const float*)d_in[3];
  const float* b   = (const float*)d_in[4];
  float* out = (float*)d_out;
  unsigned short* supportT = (unsigned short*)d_ws;  // 64 x 16384 bf16 = 2 MiB

  support_kernel<<<N_NODES / 4, 256, 0, stream>>>(x, W, supportT);
  gcn_agg_kernel<<<N_NODES / 64, 256, 0, stream>>>(adj, supportT, dn, b, out);
}